// Round 1
// baseline (369.147 us; speedup 1.0000x reference)
//
#include <hip/hip_runtime.h>
#include <hip/hip_bf16.h>
#include <math.h>

#define TOKENS 16384
#define DIM    2048
#define NEXP   16

// Layout: wave64 = 8 tokens x 8-lane k-split.
//   lane = tloc*8 + sub ; sub in [0,8) splits K, tloc in [0,8) is token-in-wave
//   x float4 index within a row: j*8 + sub, j = 0..63  (contiguous 128B per token per instr)
// block = 256 thr (4 waves) = 32 tokens ; grid = 512 blocks = 2 blocks/CU, 8 waves/CU.
__global__ __launch_bounds__(256, 2) void gating_moe_kernel(
    const float* __restrict__ x,
    const float* __restrict__ noise,
    const float* __restrict__ W,
    const float* __restrict__ b,
    float* __restrict__ out)
{
    const int tid   = threadIdx.x;
    const int lane  = tid & 63;
    const int waveI = tid >> 6;
    const int sub   = lane & 7;   // k-split slot
    const int tloc  = lane >> 3;  // token within wave
    const int token = blockIdx.x * 32 + waveI * 8 + tloc;
    if (token >= TOKENS) return;

    float acc[NEXP];
#pragma unroll
    for (int e = 0; e < NEXP; ++e) acc[e] = 0.0f;

    const float4* __restrict__ xr = (const float4*)(x + (size_t)token * DIM);

#pragma unroll 4
    for (int j = 0; j < DIM / 32; ++j) {
        const int idx = j * 8 + sub;       // float4 index in row
        float4 xv = xr[idx];
#pragma unroll
        for (int e = 0; e < NEXP; ++e) {
            float4 wv = ((const float4*)(W + (size_t)e * DIM))[idx];
            acc[e] = fmaf(xv.x, wv.x,
                     fmaf(xv.y, wv.y,
                     fmaf(xv.z, wv.z,
                     fmaf(xv.w, wv.w, acc[e]))));
        }
    }

    // Reduce across the 8 k-split lanes of this token (lanes are consecutive).
#pragma unroll
    for (int e = 0; e < NEXP; ++e) {
        acc[e] += __shfl_xor(acc[e], 1);
        acc[e] += __shfl_xor(acc[e], 2);
        acc[e] += __shfl_xor(acc[e], 4);
    }

    // All 8 lanes now hold the full 16 dot products. Add bias + 0.1*noise
    // (redundantly per lane; compile-time indices only).
    const float4* __restrict__ nz4 = (const float4*)(noise + (size_t)token * NEXP);
    float noisy[NEXP];
#pragma unroll
    for (int q = 0; q < 4; ++q) {
        float4 nv = nz4[q];
        noisy[q * 4 + 0] = acc[q * 4 + 0] + b[q * 4 + 0] + 0.1f * nv.x;
        noisy[q * 4 + 1] = acc[q * 4 + 1] + b[q * 4 + 1] + 0.1f * nv.y;
        noisy[q * 4 + 2] = acc[q * 4 + 2] + b[q * 4 + 2] + 0.1f * nv.z;
        noisy[q * 4 + 3] = acc[q * 4 + 3] + b[q * 4 + 3] + 0.1f * nv.w;
    }

    // Top-2 (ties -> lowest index, matching jax.lax.top_k).
    float v1 = -INFINITY; int i1 = -1;
#pragma unroll
    for (int e = 0; e < NEXP; ++e) {
        bool g = noisy[e] > v1;
        v1 = g ? noisy[e] : v1;
        i1 = g ? e : i1;
    }
    float v2 = -INFINITY; int i2 = -1;
#pragma unroll
    for (int e = 0; e < NEXP; ++e) {
        bool g = (e != i1) && (noisy[e] > v2);
        v2 = g ? noisy[e] : v2;
        i2 = g ? e : i2;
    }

    // Softmax over {v1, v2} with v1 >= v2.
    float d  = __expf(v2 - v1);
    float w1 = 1.0f / (1.0f + d);
    float w2 = d * w1;

    // Each lane writes its 2 expert slots (float2, fully coalesced).
    const int e0 = sub * 2;
    const int e1 = e0 + 1;
    float o0 = (e0 == i1) ? w1 : ((e0 == i2) ? w2 : 0.0f);
    float o1 = (e1 == i1) ? w1 : ((e1 == i2) ? w2 : 0.0f);
    float2 o = make_float2(o0, o1);
    ((float2*)(out + (size_t)token * NEXP))[sub] = o;
}

extern "C" void kernel_launch(void* const* d_in, const int* in_sizes, int n_in,
                              void* d_out, int out_size, void* d_ws, size_t ws_size,
                              hipStream_t stream) {
    const float* x     = (const float*)d_in[0];
    const float* noise = (const float*)d_in[1];
    const float* W     = (const float*)d_in[2];
    const float* b     = (const float*)d_in[3];
    float* out = (float*)d_out;

    dim3 grid(TOKENS / 32);   // 512 blocks
    dim3 block(256);
    gating_moe_kernel<<<grid, block, 0, stream>>>(x, noise, W, b, out);
}

// Round 3
// 214.250 us; speedup vs baseline: 1.7230x; 1.7230x over previous
//
#include <hip/hip_runtime.h>
#include <hip/hip_bf16.h>
#include <math.h>

#define TOKENS 16384
#define DIM    2048
#define NEXP   16

// Native clang vector type (works with __builtin_nontemporal_load, unlike
// HIP's struct-based float4).
typedef float fvec4 __attribute__((ext_vector_type(4)));

// Layout: wave64 = 2 token-slots x 32-lane k-split.
//   sub  = lane & 31  : k-split slot; lane covers fvec4 col idx j*32+sub, j in [0,16)
//   tslot= lane >> 5  : token-pair slot; lane accumulates tokens t0 = base+tslot*2 and t0+1
// 4 tokens/wave, block 256 (4 waves) = 16 tokens, grid 1024 = 4 blocks/CU, 16 waves/CU.
// Loads per j-iter: 2 x(fvec4, nontemporal) + 16 W(fvec4, L1-resident) feeding 128 FMAs.

__device__ __forceinline__ float fma4(fvec4 a, fvec4 w, float acc) {
    return fmaf(a.x, w.x, fmaf(a.y, w.y, fmaf(a.z, w.z, fmaf(a.w, w.w, acc))));
}

__global__ __launch_bounds__(256, 4) void gating_moe_kernel(
    const float* __restrict__ x,
    const float* __restrict__ noise,
    const float* __restrict__ W,
    const float* __restrict__ b,
    float* __restrict__ out)
{
    const int tid   = threadIdx.x;
    const int lane  = tid & 63;
    const int waveI = tid >> 6;
    const int sub   = lane & 31;
    const int tslot = lane >> 5;
    const int tokbase = blockIdx.x * 16 + waveI * 4;
    const int t0 = tokbase + tslot * 2;      // this lane's token pair: t0, t0+1

    float acc0[NEXP], acc1[NEXP];
#pragma unroll
    for (int e = 0; e < NEXP; ++e) { acc0[e] = 0.0f; acc1[e] = 0.0f; }

    const fvec4* __restrict__ xr0 = (const fvec4*)(x + (size_t)t0 * DIM);
    const fvec4* __restrict__ xr1 = xr0 + (DIM / 4);
    const fvec4* __restrict__ Wv  = (const fvec4*)W;

#pragma unroll 2
    for (int j = 0; j < 16; ++j) {
        const int idx = j * 32 + sub;
        fvec4 xa = __builtin_nontemporal_load(&xr0[idx]);
        fvec4 xb = __builtin_nontemporal_load(&xr1[idx]);
        fvec4 wv[8];
#pragma unroll
        for (int e = 0; e < 8; ++e) wv[e] = Wv[e * (DIM / 4) + idx];
#pragma unroll
        for (int e = 0; e < 8; ++e) {
            acc0[e] = fma4(xa, wv[e], acc0[e]);
            acc1[e] = fma4(xb, wv[e], acc1[e]);
        }
#pragma unroll
        for (int e = 0; e < 8; ++e) wv[e] = Wv[(e + 8) * (DIM / 4) + idx];
#pragma unroll
        for (int e = 0; e < 8; ++e) {
            acc0[e + 8] = fma4(xa, wv[e], acc0[e + 8]);
            acc1[e + 8] = fma4(xb, wv[e], acc1[e + 8]);
        }
    }

    // ---- Reduce across the 32 k-split lanes ----
    // Step 1: xor 1,2,4,8 -> each lane holds its 16-lane group's partial for BOTH tokens.
#pragma unroll
    for (int e = 0; e < NEXP; ++e) {
        acc0[e] += __shfl_xor(acc0[e], 1);  acc1[e] += __shfl_xor(acc1[e], 1);
        acc0[e] += __shfl_xor(acc0[e], 2);  acc1[e] += __shfl_xor(acc1[e], 2);
        acc0[e] += __shfl_xor(acc0[e], 4);  acc1[e] += __shfl_xor(acc1[e], 4);
        acc0[e] += __shfl_xor(acc0[e], 8);  acc1[e] += __shfl_xor(acc1[e], 8);
    }
    // Step 2: lane's write-token r = bit4 of sub. Send the OTHER token's partial
    // across xor16; receive the partner group's partial of MY token.
    const int r = (sub >> 4) & 1;
    float full[NEXP];
#pragma unroll
    for (int e = 0; e < NEXP; ++e) {
        float mine = r ? acc1[e] : acc0[e];
        float send = r ? acc0[e] : acc1[e];
        full[e] = mine + __shfl_xor(send, 16);
    }

    // ---- Epilogue: bias + noise, top-2, softmax (per-lane, for token t0+r) ----
    const int token = t0 + r;
    const fvec4* __restrict__ nz4 = (const fvec4*)(noise + (size_t)token * NEXP);
    float noisy[NEXP];
#pragma unroll
    for (int q = 0; q < 4; ++q) {
        fvec4 nv = __builtin_nontemporal_load(&nz4[q]);
        noisy[q * 4 + 0] = full[q * 4 + 0] + b[q * 4 + 0] + 0.1f * nv.x;
        noisy[q * 4 + 1] = full[q * 4 + 1] + b[q * 4 + 1] + 0.1f * nv.y;
        noisy[q * 4 + 2] = full[q * 4 + 2] + b[q * 4 + 2] + 0.1f * nv.z;
        noisy[q * 4 + 3] = full[q * 4 + 3] + b[q * 4 + 3] + 0.1f * nv.w;
    }

    // Top-2, ties -> lowest index (matches jax.lax.top_k).
    float v1 = -INFINITY; int i1 = -1;
#pragma unroll
    for (int e = 0; e < NEXP; ++e) {
        bool g = noisy[e] > v1;
        v1 = g ? noisy[e] : v1;
        i1 = g ? e : i1;
    }
    float v2 = -INFINITY; int i2 = -1;
#pragma unroll
    for (int e = 0; e < NEXP; ++e) {
        bool g = (e != i1) && (noisy[e] > v2);
        v2 = g ? noisy[e] : v2;
        i2 = g ? e : i2;
    }

    float d  = __expf(v2 - v1);
    float w1 = 1.0f / (1.0f + d);
    float w2 = d * w1;

    // Each lane writes ONE float: expert e = sub & 15 of its token.
    // out index = token*16 + e = tokbase*16 + lane  -> 256B contiguous per wave.
    const int e = sub & 15;
    float o = (e == i1) ? w1 : ((e == i2) ? w2 : 0.0f);
    out[(size_t)tokbase * NEXP + lane] = o;
}

extern "C" void kernel_launch(void* const* d_in, const int* in_sizes, int n_in,
                              void* d_out, int out_size, void* d_ws, size_t ws_size,
                              hipStream_t stream) {
    const float* x     = (const float*)d_in[0];
    const float* noise = (const float*)d_in[1];
    const float* W     = (const float*)d_in[2];
    const float* b     = (const float*)d_in[3];
    float* out = (float*)d_out;

    dim3 grid(TOKENS / 16);   // 1024 blocks
    dim3 block(256);
    gating_moe_kernel<<<grid, block, 0, stream>>>(x, noise, W, b, out);
}

// Round 4
// 211.257 us; speedup vs baseline: 1.7474x; 1.0142x over previous
//
#include <hip/hip_runtime.h>
#include <hip/hip_bf16.h>
#include <math.h>

#define TOKENS 16384
#define DIM    2048
#define NEXP   16

typedef float fvec4 __attribute__((ext_vector_type(4)));

// Layout: wave64 = 2 token-groups x 32-lane k-split, 4 tokens per lane.
//   sub    = lane & 31 : k-split slot; lane covers fvec4 col idx j*32+sub, j in [0,16)
//   tgroup = lane >> 5 : token-group; lane accumulates tokens t0..t0+3,
//                        t0 = wave_base + tgroup*4  -> 8 tokens/wave.
// Block 256 (4 waves) = 32 tokens, grid 512 = ~2-3 blocks/CU.
// Per j-iter: 4 x loads + 16 W loads = 20 VMEM feeding 256 FMAs
// (W bytes amortized over 4 tokens -> half the L1/L2 W traffic of R3).

__device__ __forceinline__ float fma4(fvec4 a, fvec4 w, float acc) {
    return fmaf(a.x, w.x, fmaf(a.y, w.y, fmaf(a.z, w.z, fmaf(a.w, w.w, acc))));
}

__global__ __launch_bounds__(256, 2) void gating_moe_kernel(
    const float* __restrict__ x,
    const float* __restrict__ noise,
    const float* __restrict__ W,
    const float* __restrict__ b,
    float* __restrict__ out)
{
    const int tid   = threadIdx.x;
    const int lane  = tid & 63;
    const int waveI = tid >> 6;
    const int sub   = lane & 31;
    const int tgroup = lane >> 5;
    const int wave_base = blockIdx.x * 32 + waveI * 8;   // 8 tokens per wave
    const int t0 = wave_base + tgroup * 4;               // this lane's 4 tokens

    float acc[4][NEXP];
#pragma unroll
    for (int t = 0; t < 4; ++t)
#pragma unroll
        for (int e = 0; e < NEXP; ++e) acc[t][e] = 0.0f;

    const fvec4* __restrict__ xr = (const fvec4*)(x + (size_t)t0 * DIM);
    const fvec4* __restrict__ Wv = (const fvec4*)W;
    const int ROW = DIM / 4;   // fvec4 per row

#pragma unroll 2
    for (int j = 0; j < 16; ++j) {
        const int idx = j * 32 + sub;
        fvec4 xv[4];
#pragma unroll
        for (int t = 0; t < 4; ++t) xv[t] = xr[t * ROW + idx];

        fvec4 wv[8];
#pragma unroll
        for (int e = 0; e < 8; ++e) wv[e] = Wv[e * ROW + idx];
#pragma unroll
        for (int e = 0; e < 8; ++e)
#pragma unroll
            for (int t = 0; t < 4; ++t)
                acc[t][e] = fma4(xv[t], wv[e], acc[t][e]);

#pragma unroll
        for (int e = 0; e < 8; ++e) wv[e] = Wv[(e + 8) * ROW + idx];
#pragma unroll
        for (int e = 0; e < 8; ++e)
#pragma unroll
            for (int t = 0; t < 4; ++t)
                acc[t][e + 8] = fma4(xv[t], wv[e], acc[t][e + 8]);
    }

    // ---- Reduce across the 32 k-split lanes (xor 1..16 stays within the
    // 32-lane half, so the two token-groups reduce independently). ----
#pragma unroll
    for (int t = 0; t < 4; ++t)
#pragma unroll
        for (int e = 0; e < NEXP; ++e) {
            float v = acc[t][e];
            v += __shfl_xor(v, 1);
            v += __shfl_xor(v, 2);
            v += __shfl_xor(v, 4);
            v += __shfl_xor(v, 8);
            v += __shfl_xor(v, 16);
            acc[t][e] = v;   // all 32 lanes of the half now hold the full sum
        }

    // ---- Per-lane token select (compile-time acc indices, cndmask chain).
    // Lane handles token wtok = wave_base + (lane>>3); lanes 0..31 want
    // tokens 0..3 (their own group), lanes 32..63 want 4..7 (their own group):
    // local index tsel = (lane>>3)&3.  8 lanes per token.
    const int tsel  = (lane >> 3) & 3;
    const int token = wave_base + (lane >> 3);

    float full[NEXP];
#pragma unroll
    for (int e = 0; e < NEXP; ++e) {
        float v = acc[0][e];
        v = (tsel == 1) ? acc[1][e] : v;
        v = (tsel == 2) ? acc[2][e] : v;
        v = (tsel == 3) ? acc[3][e] : v;
        full[e] = v;
    }

    // ---- Epilogue: bias + 0.1*noise, top-2, softmax (redundant per 8 lanes).
    const fvec4* __restrict__ nz4 = (const fvec4*)(noise + (size_t)token * NEXP);
    float noisy[NEXP];
#pragma unroll
    for (int q = 0; q < 4; ++q) {
        fvec4 nv = nz4[q];
        noisy[q * 4 + 0] = full[q * 4 + 0] + b[q * 4 + 0] + 0.1f * nv.x;
        noisy[q * 4 + 1] = full[q * 4 + 1] + b[q * 4 + 1] + 0.1f * nv.y;
        noisy[q * 4 + 2] = full[q * 4 + 2] + b[q * 4 + 2] + 0.1f * nv.z;
        noisy[q * 4 + 3] = full[q * 4 + 3] + b[q * 4 + 3] + 0.1f * nv.w;
    }

    // Top-2, ties -> lowest index (matches jax.lax.top_k).
    float v1 = -INFINITY; int i1 = -1;
#pragma unroll
    for (int e = 0; e < NEXP; ++e) {
        bool g = noisy[e] > v1;
        v1 = g ? noisy[e] : v1;
        i1 = g ? e : i1;
    }
    float v2 = -INFINITY; int i2 = -1;
#pragma unroll
    for (int e = 0; e < NEXP; ++e) {
        bool g = (e != i1) && (noisy[e] > v2);
        v2 = g ? noisy[e] : v2;
        i2 = g ? e : i2;
    }

    float d  = __expf(v2 - v1);
    float w1 = 1.0f / (1.0f + d);
    float w2 = d * w1;

    // Lane writes experts {2q, 2q+1}, q = lane&7, of its token as float2.
    // out index = token*16 + 2q = wave_base*16 + lane*2  -> 512B contiguous/wave.
    const int e0 = (lane & 7) * 2;
    const int e1 = e0 + 1;
    float o0 = (e0 == i1) ? w1 : ((e0 == i2) ? w2 : 0.0f);
    float o1 = (e1 == i1) ? w1 : ((e1 == i2) ? w2 : 0.0f);
    float2 o = make_float2(o0, o1);
    ((float2*)(out + (size_t)token * NEXP))[lane & 7] = o;
}

extern "C" void kernel_launch(void* const* d_in, const int* in_sizes, int n_in,
                              void* d_out, int out_size, void* d_ws, size_t ws_size,
                              hipStream_t stream) {
    const float* x     = (const float*)d_in[0];
    const float* noise = (const float*)d_in[1];
    const float* W     = (const float*)d_in[2];
    const float* b     = (const float*)d_in[3];
    float* out = (float*)d_out;

    dim3 grid(TOKENS / 32);   // 512 blocks
    dim3 block(256);
    gating_moe_kernel<<<grid, block, 0, stream>>>(x, noise, W, b, out);
}